// Round 2
// baseline (767.464 us; speedup 1.0000x reference)
//
#include <hip/hip_runtime.h>

typedef unsigned int u32;

// ---------- workspace layout (fp32 elements) ----------
#define WS_WQ   0        // [128][64]  Wq with z_ln_g folded into rows
#define WS_WK   8192     // [64][64]   Wk with t_ln_g folded
#define WS_WV   12288    // [64][64]   Wv with t_ln_g folded
#define WS_WOT  16384    // [128][64]  Wo transposed: WOT[m][hc] = Wo[hc][m]
#define WS_BO   24576    // [128]
#define WS_GQ   24704    // [64] sum_d z_ln_g[d]*Wq[d][hc]
#define WS_BQ   24768    // [64] sum_d z_ln_b[d]*Wq[d][hc]
#define WS_GK   24832    // [64]
#define WS_BK   24896    // [64]
#define WS_GV   24960    // [64]
#define WS_BV   25024    // [64]

__global__ void prep_a(const float* __restrict__ Wq, const float* __restrict__ Wk,
                       const float* __restrict__ Wv, const float* __restrict__ Wo,
                       const float* __restrict__ bo, const float* __restrict__ zg,
                       const float* __restrict__ tg, float* __restrict__ ws) {
    int idx = blockIdx.x * blockDim.x + threadIdx.x;
    if (idx < 8192) {
        ws[WS_WQ + idx] = Wq[idx] * zg[idx >> 6];
    } else if (idx < 12288) {
        int e = idx - 8192;
        ws[idx] = Wk[e] * tg[e >> 6];
    } else if (idx < 16384) {
        int e = idx - 12288;
        ws[idx] = Wv[e] * tg[e >> 6];
    } else if (idx < 24576) {
        int e = idx - 16384; int m = e >> 6; int hc = e & 63;
        ws[idx] = Wo[hc * 128 + m];
    } else if (idx < 24704) {
        ws[idx] = bo[idx - 24576];
    }
}

__global__ void prep_b(const float* __restrict__ Wq, const float* __restrict__ Wk,
                       const float* __restrict__ Wv, const float* __restrict__ zg,
                       const float* __restrict__ zb, const float* __restrict__ tg,
                       const float* __restrict__ tb, float* __restrict__ ws) {
    int idx = blockIdx.x * blockDim.x + threadIdx.x;
    if (idx >= 384) return;
    int g = idx >> 6, hc = idx & 63;
    float acc = 0.f;
    if (g == 0)      { for (int d = 0; d < 128; ++d) acc += zg[d] * Wq[d*64+hc]; ws[WS_GQ+hc] = acc; }
    else if (g == 1) { for (int d = 0; d < 128; ++d) acc += zb[d] * Wq[d*64+hc]; ws[WS_BQ+hc] = acc; }
    else if (g == 2) { for (int d = 0; d < 64;  ++d) acc += tg[d] * Wk[d*64+hc]; ws[WS_GK+hc] = acc; }
    else if (g == 3) { for (int d = 0; d < 64;  ++d) acc += tb[d] * Wk[d*64+hc]; ws[WS_BK+hc] = acc; }
    else if (g == 4) { for (int d = 0; d < 64;  ++d) acc += tg[d] * Wv[d*64+hc]; ws[WS_GV+hc] = acc; }
    else             { for (int d = 0; d < 64;  ++d) acc += tb[d] * Wv[d*64+hc]; ws[WS_BV+hc] = acc; }
}

// one thread per (i,j) pair; 576 blocks x 256 threads = 147456 pairs exactly
__global__ __launch_bounds__(256, 2) void tpa_main(
    const float* __restrict__ tmpl,   // [4][384][384][64] f32
    const float* __restrict__ z,      // [384][384][128] f32
    const float* __restrict__ mask,   // [4][384] f32 (0/1)
    const float* __restrict__ ws,
    float* __restrict__ out)          // [384][384][128] f32
{
    const float* __restrict__ wq  = ws + WS_WQ;
    const float* __restrict__ wk  = ws + WS_WK;
    const float* __restrict__ wv  = ws + WS_WV;
    const float* __restrict__ wot = ws + WS_WOT;
    const float* __restrict__ bo  = ws + WS_BO;
    const float* __restrict__ GQ  = ws + WS_GQ;
    const float* __restrict__ BQ  = ws + WS_BQ;
    const float* __restrict__ GK  = ws + WS_GK;
    const float* __restrict__ BK  = ws + WS_BK;
    const float* __restrict__ GV  = ws + WS_GV;
    const float* __restrict__ BV  = ws + WS_BV;

    const int p = blockIdx.x * 256 + threadIdx.x;
    const int i = p / 384;
    const int j = p - i * 384;

    // ---------- q = LN(z) @ Wq  (stats fused; LN applied as affine correction) ----------
    float q[64];
    #pragma unroll
    for (int hc = 0; hc < 64; ++hc) q[hc] = 0.f;
    float zs = 0.f, zs2 = 0.f;
    const float4* z4 = reinterpret_cast<const float4*>(z + (size_t)p * 128);
    #pragma unroll 1
    for (int c = 0; c < 32; ++c) {
        float4 u = z4[c];
        float f[4] = {u.x, u.y, u.z, u.w};
        const float* wr = wq + c * 256;
        #pragma unroll
        for (int dd = 0; dd < 4; ++dd) {
            float zv = f[dd];
            zs += zv; zs2 = fmaf(zv, zv, zs2);
            const float* w = wr + dd * 64;
            #pragma unroll
            for (int hc = 0; hc < 64; ++hc) q[hc] = fmaf(zv, w[hc], q[hc]);
        }
    }
    {
        float mu  = zs * (1.f / 128.f);
        float var = fmaf(-mu, mu, zs2 * (1.f / 128.f));
        float r   = rsqrtf(var + 1e-5f);
        float rm  = r * mu;
        #pragma unroll
        for (int hc = 0; hc < 64; ++hc)
            q[hc] = fmaf(r, q[hc], fmaf(-rm, GQ[hc], BQ[hc]));
    }

    // per-head q·GK, q·BK (for the LN affine correction of k)
    float qgk[4], qbk[4];
    #pragma unroll
    for (int h = 0; h < 4; ++h) {
        float a = 0.f, b = 0.f;
        #pragma unroll
        for (int c = 0; c < 16; ++c) {
            a = fmaf(q[h*16+c], GK[h*16+c], a);
            b = fmaf(q[h*16+c], BK[h*16+c], b);
        }
        qgk[h] = a; qbk[h] = b;
    }

    // ---------- pass 1: raw logits for all 4 templates, t-stats fused ----------
    const float4* t0 = reinterpret_cast<const float4*>(tmpl + ((size_t)0*147456 + p) * 64);
    const float4* t1 = reinterpret_cast<const float4*>(tmpl + ((size_t)1*147456 + p) * 64);
    const float4* t2 = reinterpret_cast<const float4*>(tmpl + ((size_t)2*147456 + p) * 64);
    const float4* t3 = reinterpret_cast<const float4*>(tmpl + ((size_t)3*147456 + p) * 64);

    float lg[16];
    #pragma unroll
    for (int x = 0; x < 16; ++x) lg[x] = 0.f;
    float ts0=0,ts1=0,ts2=0,ts3=0, tq0=0,tq1=0,tq2=0,tq3=0;
    #pragma unroll 1
    for (int c = 0; c < 16; ++c) {
        float4 ua=t0[c], ub=t1[c], uc=t2[c], ud=t3[c];
        float fa[4]={ua.x,ua.y,ua.z,ua.w}, fb[4]={ub.x,ub.y,ub.z,ub.w};
        float fc[4]={uc.x,uc.y,uc.z,uc.w}, fd[4]={ud.x,ud.y,ud.z,ud.w};
        const float* wr = wk + c * 256;
        #pragma unroll
        for (int dd = 0; dd < 4; ++dd) {
            const float* w = wr + dd * 64;
            // per-d projection q · Wk'[d] per head — shared across all 4 templates
            float p0=0.f,p1=0.f,p2=0.f,p3=0.f;
            #pragma unroll
            for (int cc = 0; cc < 16; ++cc) {
                p0 = fmaf(q[cc],    w[cc],    p0);
                p1 = fmaf(q[16+cc], w[16+cc], p1);
                p2 = fmaf(q[32+cc], w[32+cc], p2);
                p3 = fmaf(q[48+cc], w[48+cc], p3);
            }
            float va=fa[dd], vb=fb[dd], vc=fc[dd], vd=fd[dd];
            ts0+=va; tq0=fmaf(va,va,tq0);
            ts1+=vb; tq1=fmaf(vb,vb,tq1);
            ts2+=vc; tq2=fmaf(vc,vc,tq2);
            ts3+=vd; tq3=fmaf(vd,vd,tq3);
            lg[0] =fmaf(va,p0,lg[0]);  lg[1] =fmaf(va,p1,lg[1]);  lg[2] =fmaf(va,p2,lg[2]);  lg[3] =fmaf(va,p3,lg[3]);
            lg[4] =fmaf(vb,p0,lg[4]);  lg[5] =fmaf(vb,p1,lg[5]);  lg[6] =fmaf(vb,p2,lg[6]);  lg[7] =fmaf(vb,p3,lg[7]);
            lg[8] =fmaf(vc,p0,lg[8]);  lg[9] =fmaf(vc,p1,lg[9]);  lg[10]=fmaf(vc,p2,lg[10]); lg[11]=fmaf(vc,p3,lg[11]);
            lg[12]=fmaf(vd,p0,lg[12]); lg[13]=fmaf(vd,p1,lg[13]); lg[14]=fmaf(vd,p2,lg[14]); lg[15]=fmaf(vd,p3,lg[15]);
        }
    }

    // ---------- finalize logits (LN affine correction + scale + mask) ----------
    float rsv[4], rmv[4], pm[4];
    {
        float tsA[4] = {ts0,ts1,ts2,ts3};
        float tqA[4] = {tq0,tq1,tq2,tq3};
        #pragma unroll
        for (int tt = 0; tt < 4; ++tt) {
            float mu  = tsA[tt] * (1.f / 64.f);
            float var = fmaf(-mu, mu, tqA[tt] * (1.f / 64.f));
            float r   = rsqrtf(var + 1e-5f);
            rsv[tt] = r; rmv[tt] = r * mu;
            float mi = mask[tt*384 + i];
            float mj = mask[tt*384 + j];
            pm[tt] = mi * mj;
            #pragma unroll
            for (int h = 0; h < 4; ++h) {
                float lfin = 0.25f * fmaf(r, lg[tt*4+h], fmaf(-rmv[tt], qgk[h], qbk[h]));
                lg[tt*4+h] = (pm[tt] == 0.f) ? -1e9f : lfin;
            }
        }
    }

    // ---------- softmax over T (per head) + mask renorm ----------
    float aw[16];   // attn * rstd_t  (for the raw-v part)
    float cB[4], cG[4];
    #pragma unroll
    for (int h = 0; h < 4; ++h) {
        float l0=lg[h], l1=lg[4+h], l2=lg[8+h], l3=lg[12+h];
        float mx = fmaxf(fmaxf(l0,l1), fmaxf(l2,l3));
        float e0=__expf(l0-mx), e1=__expf(l1-mx), e2=__expf(l2-mx), e3=__expf(l3-mx);
        float inv = 1.f / (e0+e1+e2+e3);
        float a0=e0*inv*pm[0], a1=e1*inv*pm[1], a2=e2*inv*pm[2], a3=e3*inv*pm[3];
        float ssum = a0+a1+a2+a3;
        float rr = 1.f / fmaxf(ssum, 1e-8f);
        a0*=rr; a1*=rr; a2*=rr; a3*=rr;
        aw[0*4+h]=a0*rsv[0]; aw[1*4+h]=a1*rsv[1]; aw[2*4+h]=a2*rsv[2]; aw[3*4+h]=a3*rsv[3];
        cB[h] = a0+a1+a2+a3;
        cG[h] = a0*rmv[0] + a1*rmv[1] + a2*rmv[2] + a3*rmv[3];
    }

    // ---------- pass 2: o[hc] = sum_t attn * (LN(t) @ Wv) ----------
    float o[64];
    #pragma unroll
    for (int hc = 0; hc < 64; ++hc) o[hc] = 0.f;
    #pragma unroll 1
    for (int c = 0; c < 16; ++c) {
        float4 ua=t0[c], ub=t1[c], uc=t2[c], ud=t3[c];
        float fa[4]={ua.x,ua.y,ua.z,ua.w}, fb[4]={ub.x,ub.y,ub.z,ub.w};
        float fc[4]={uc.x,uc.y,uc.z,uc.w}, fd[4]={ud.x,ud.y,ud.z,ud.w};
        const float* wr = wv + c * 256;
        #pragma unroll
        for (int dd = 0; dd < 4; ++dd) {
            float va=fa[dd], vb=fb[dd], vc=fc[dd], vd=fd[dd];
            float c0 = fmaf(aw[0], va, fmaf(aw[4], vb, fmaf(aw[8],  vc, aw[12]*vd)));
            float c1 = fmaf(aw[1], va, fmaf(aw[5], vb, fmaf(aw[9],  vc, aw[13]*vd)));
            float c2 = fmaf(aw[2], va, fmaf(aw[6], vb, fmaf(aw[10], vc, aw[14]*vd)));
            float c3 = fmaf(aw[3], va, fmaf(aw[7], vb, fmaf(aw[11], vc, aw[15]*vd)));
            const float* w = wr + dd * 64;
            #pragma unroll
            for (int cc = 0; cc < 16; ++cc) {
                o[cc]    = fmaf(c0, w[cc],    o[cc]);
                o[16+cc] = fmaf(c1, w[16+cc], o[16+cc]);
                o[32+cc] = fmaf(c2, w[32+cc], o[32+cc]);
                o[48+cc] = fmaf(c3, w[48+cc], o[48+cc]);
            }
        }
    }
    // LN affine correction for v, weighted by attention sums
    #pragma unroll
    for (int hc = 0; hc < 64; ++hc) {
        int h = hc >> 4;
        o[hc] = fmaf(cB[h], BV[hc], fmaf(-cG[h], GV[hc], o[hc]));
    }

    // ---------- out = o @ Wo + bo ----------
    float4* ov = reinterpret_cast<float4*>(out + (size_t)p * 128);
    #pragma unroll 1
    for (int mc = 0; mc < 32; ++mc) {
        float r[4];
        #pragma unroll
        for (int mm = 0; mm < 4; ++mm) {
            int m = mc*4 + mm;
            float acc = bo[m];
            const float* w = wot + m*64;
            #pragma unroll
            for (int hc = 0; hc < 64; ++hc) acc = fmaf(o[hc], w[hc], acc);
            r[mm] = acc;
        }
        float4 pk; pk.x = r[0]; pk.y = r[1]; pk.z = r[2]; pk.w = r[3];
        ov[mc] = pk;
    }
}

extern "C" void kernel_launch(void* const* d_in, const int* in_sizes, int n_in,
                              void* d_out, int out_size, void* d_ws, size_t ws_size,
                              hipStream_t stream) {
    const float* t   = (const float*)d_in[0];
    const float* z   = (const float*)d_in[1];
    const float* msk = (const float*)d_in[2];
    const float* zg  = (const float*)d_in[3];
    const float* zb  = (const float*)d_in[4];
    const float* tg  = (const float*)d_in[5];
    const float* tb  = (const float*)d_in[6];
    const float* Wq  = (const float*)d_in[7];
    const float* Wk  = (const float*)d_in[8];
    const float* Wv  = (const float*)d_in[9];
    const float* Wo  = (const float*)d_in[10];
    const float* bo  = (const float*)d_in[11];
    float* ws = (float*)d_ws;

    prep_a<<<97, 256, 0, stream>>>(Wq, Wk, Wv, Wo, bo, zg, tg, ws);
    prep_b<<<2, 256, 0, stream>>>(Wq, Wk, Wv, zg, zb, tg, tb, ws);
    tpa_main<<<576, 256, 0, stream>>>(t, z, msk, ws, (float*)d_out);
}

// Round 3
// 334.615 us; speedup vs baseline: 2.2936x; 2.2936x over previous
//
#include <hip/hip_runtime.h>

typedef unsigned int u32;
typedef unsigned short u16;
typedef __attribute__((ext_vector_type(8))) short short8;
typedef __attribute__((ext_vector_type(4))) float f4;

#define MFMA(a, b, c) __builtin_amdgcn_mfma_f32_16x16x32_bf16((a), (b), (c), 0, 0, 0)
#define LL 384
#define NPAIR 147456

// ---- helpers ----
__device__ __forceinline__ u16 f2bf(float f) {
    u32 u = __float_as_uint(f);
    u = (u + 0x7fffu + ((u >> 16) & 1u)) >> 16;
    return (u16)u;
}
__device__ __forceinline__ u32 pack2(float a, float b) {
    u32 ua = __float_as_uint(a); ua = (ua + 0x7fffu + ((ua >> 16) & 1u)) >> 16;
    u32 ub = __float_as_uint(b); ub = (ub + 0x7fffu + ((ub >> 16) & 1u)) >> 16;
    return ua | (ub << 16);
}
__device__ __forceinline__ short8 ld8(const u16* p) { return *reinterpret_cast<const short8*>(p); }
__device__ __forceinline__ float red16(float v) {
    v += __shfl_xor(v, 1);
    v += __shfl_xor(v, 2);
    v += __shfl_xor(v, 4);
    v += __shfl_xor(v, 8);
    return v;
}

// ---- workspace layout ----
// u16 region: [0,8192) WqSW  [8192,12288) WkSW  [12288,16384) WvSW  [16384,24576) WoSW
// float region (float idx): [12288..] GQ BQ GK BK GV BV (64 each), bo at 12672 (128)
// swizzle: sw[(k>>3)*N*8 + n*8 + (k&7)] = W'[k][n]

__global__ void prep_w(const float* __restrict__ Wq, const float* __restrict__ Wk,
                       const float* __restrict__ Wv, const float* __restrict__ Wo,
                       const float* __restrict__ zg, const float* __restrict__ tg,
                       float* __restrict__ ws) {
    int idx = blockIdx.x * blockDim.x + threadIdx.x;
    u16* wsu = (u16*)ws;
    if (idx < 8192) {               // WqSW, N=64, K=128, fold zg
        int kb = idx >> 9, rem = idx & 511, n = rem >> 3, j = rem & 7, k = kb * 8 + j;
        wsu[idx] = f2bf(Wq[k * 64 + n] * zg[k]);
    } else if (idx < 12288) {       // WkSW, N=64, K=64, fold tg
        int e = idx - 8192;
        int kb = e >> 9, rem = e & 511, n = rem >> 3, j = rem & 7, k = kb * 8 + j;
        wsu[idx] = f2bf(Wk[k * 64 + n] * tg[k]);
    } else if (idx < 16384) {       // WvSW
        int e = idx - 12288;
        int kb = e >> 9, rem = e & 511, n = rem >> 3, j = rem & 7, k = kb * 8 + j;
        wsu[idx] = f2bf(Wv[k * 64 + n] * tg[k]);
    } else if (idx < 24576) {       // WoSW, N=128, K=64, no fold
        int e = idx - 16384;
        int kb = e >> 10, rem = e & 1023, n = rem >> 3, j = rem & 7, k = kb * 8 + j;
        wsu[idx] = f2bf(Wo[k * 128 + n]);
    }
}

__global__ void prep_aux(const float* __restrict__ Wq, const float* __restrict__ Wk,
                         const float* __restrict__ Wv, const float* __restrict__ zg,
                         const float* __restrict__ zb, const float* __restrict__ tg,
                         const float* __restrict__ tb, const float* __restrict__ bo,
                         float* __restrict__ ws) {
    int idx = blockIdx.x * blockDim.x + threadIdx.x;
    if (idx < 384) {
        int g = idx >> 6, hc = idx & 63;
        float acc = 0.f;
        if (g == 0)      { for (int d = 0; d < 128; ++d) acc += zg[d] * Wq[d*64+hc]; ws[12288+hc] = acc; }
        else if (g == 1) { for (int d = 0; d < 128; ++d) acc += zb[d] * Wq[d*64+hc]; ws[12352+hc] = acc; }
        else if (g == 2) { for (int d = 0; d < 64;  ++d) acc += tg[d] * Wk[d*64+hc]; ws[12416+hc] = acc; }
        else if (g == 3) { for (int d = 0; d < 64;  ++d) acc += tb[d] * Wk[d*64+hc]; ws[12480+hc] = acc; }
        else if (g == 4) { for (int d = 0; d < 64;  ++d) acc += tg[d] * Wv[d*64+hc]; ws[12544+hc] = acc; }
        else             { for (int d = 0; d < 64;  ++d) acc += tb[d] * Wv[d*64+hc]; ws[12608+hc] = acc; }
    } else if (idx < 512) {
        ws[12672 + idx - 384] = bo[idx - 384];
    }
}

// block = 256 threads (4 waves), M = 32 pairs/block, grid = 4608
__global__ __launch_bounds__(256) void tpa_main(
    const float* __restrict__ tmpl,   // [4][147456][64]
    const float* __restrict__ z,      // [147456][128]
    const float* __restrict__ mask,   // [4][384]
    const float* __restrict__ ws,
    float* __restrict__ out)          // [147456][128]
{
    __shared__ __align__(16) u16 sT[4 * 32 * 72];   // t bf16, stride 72
    __shared__ __align__(16) u16 sZ[32 * 136];      // z bf16 stride 136; later o bf16 stride 72
    __shared__ __align__(16) u16 sW[8192];          // weight stage (Wq -> Wk+Wv -> Wo)
    __shared__ float sZr[32], sZrm[32];
    __shared__ float sTr[4 * 32], sTrm[4 * 32];
    __shared__ float sAux[384];                     // GQ BQ GK BK GV BV
    __shared__ float sBo[128];
    __shared__ float sPm[4 * 32];

    const int tid = threadIdx.x;
    const int p0 = blockIdx.x * 32;
    const u16* wsu = (const u16*)ws;

    // ================= phase 0: stage everything =================
    {   // weights: WqSW (1024 uint4)
        const uint4* src = (const uint4*)wsu;
        uint4* dst = (uint4*)sW;
        #pragma unroll
        for (int r = 0; r < 4; ++r) dst[tid + 256 * r] = src[tid + 256 * r];
        // aux + bo + pair-mask
        if (tid < 128) {
            sAux[tid] = ws[12288 + tid];
            sAux[128 + tid] = ws[12416 + tid];
            sAux[256 + tid] = ws[12544 + tid];
            sBo[tid] = ws[12672 + tid];
            int tt = tid >> 5, rr = tid & 31;
            int p = p0 + rr, i = p / LL, j = p - i * LL;
            sPm[tt * 32 + rr] = mask[tt * LL + i] * mask[tt * LL + j];
        }
    }
    {   // z tile: [32][128] f32, 8 threads/row
        int pp = tid >> 3, part = tid & 7;
        const float4* zg4 = (const float4*)(z + (size_t)(p0 + pp) * 128) + part * 4;
        float4 a0 = zg4[0], a1 = zg4[1], a2 = zg4[2], a3 = zg4[3];
        float s = a0.x+a0.y+a0.z+a0.w + a1.x+a1.y+a1.z+a1.w
                + a2.x+a2.y+a2.z+a2.w + a3.x+a3.y+a3.z+a3.w;
        float ss = a0.x*a0.x+a0.y*a0.y+a0.z*a0.z+a0.w*a0.w
                 + a1.x*a1.x+a1.y*a1.y+a1.z*a1.z+a1.w*a1.w
                 + a2.x*a2.x+a2.y*a2.y+a2.z*a2.z+a2.w*a2.w
                 + a3.x*a3.x+a3.y*a3.y+a3.z*a3.z+a3.w*a3.w;
        s += __shfl_xor(s, 1); ss += __shfl_xor(ss, 1);
        s += __shfl_xor(s, 2); ss += __shfl_xor(ss, 2);
        s += __shfl_xor(s, 4); ss += __shfl_xor(ss, 4);
        if (part == 0) {
            float mu = s * (1.f / 128.f);
            float var = fmaf(-mu, mu, ss * (1.f / 128.f));
            float r = rsqrtf(var + 1e-5f);
            sZr[pp] = r; sZrm[pp] = r * mu;
        }
        uint4 w0, w1;
        w0.x = pack2(a0.x, a0.y); w0.y = pack2(a0.z, a0.w);
        w0.z = pack2(a1.x, a1.y); w0.w = pack2(a1.z, a1.w);
        w1.x = pack2(a2.x, a2.y); w1.y = pack2(a2.z, a2.w);
        w1.z = pack2(a3.x, a3.y); w1.w = pack2(a3.z, a3.w);
        uint4* d = (uint4*)(sZ + pp * 136 + part * 16);
        d[0] = w0; d[1] = w1;
    }
    {   // t tiles: [4][32][64] f32, 2 threads/row
        int tt = tid >> 6, pp = (tid >> 1) & 31, part = tid & 1;
        const float4* tg4 = (const float4*)(tmpl + ((size_t)tt * NPAIR + p0 + pp) * 64) + part * 8;
        float s = 0.f, ss = 0.f;
        uint4 wbuf[4];
        #pragma unroll
        for (int c = 0; c < 4; ++c) {
            float4 b0 = tg4[c * 2], b1 = tg4[c * 2 + 1];
            s  += b0.x+b0.y+b0.z+b0.w + b1.x+b1.y+b1.z+b1.w;
            ss += b0.x*b0.x+b0.y*b0.y+b0.z*b0.z+b0.w*b0.w
                + b1.x*b1.x+b1.y*b1.y+b1.z*b1.z+b1.w*b1.w;
            wbuf[c].x = pack2(b0.x, b0.y); wbuf[c].y = pack2(b0.z, b0.w);
            wbuf[c].z = pack2(b1.x, b1.y); wbuf[c].w = pack2(b1.z, b1.w);
        }
        s += __shfl_xor(s, 1); ss += __shfl_xor(ss, 1);
        if (part == 0) {
            float mu = s * (1.f / 64.f);
            float var = fmaf(-mu, mu, ss * (1.f / 64.f));
            float r = rsqrtf(var + 1e-5f);
            sTr[tt * 32 + pp] = r; sTrm[tt * 32 + pp] = r * mu;
        }
        uint4* d = (uint4*)(sT + tt * 2304 + pp * 72 + part * 32);
        d[0] = wbuf[0]; d[1] = wbuf[1]; d[2] = wbuf[2]; d[3] = wbuf[3];
    }
    __syncthreads();

    // wave partition: rt = row-tile (16 rows), nh = n-half (2 head-tiles)
    const int wave = tid >> 6, lane = tid & 63, g = lane >> 4, l15 = lane & 15;
    const int rt = wave & 1, nh = wave >> 1;
    const int rowA = rt * 16 + l15;
    const int h0 = 2 * nh, h1 = 2 * nh + 1;
    const int col0 = h0 * 16 + l15, col1 = h1 * 16 + l15;
    int rowC[4];
    #pragma unroll
    for (int r = 0; r < 4; ++r) rowC[r] = rt * 16 + g * 4 + r;

    // ================= phase 1: q GEMM =================
    f4 aq0 = {0.f,0.f,0.f,0.f}, aq1 = {0.f,0.f,0.f,0.f};
    #pragma unroll
    for (int ks = 0; ks < 4; ++ks) {
        short8 A = ld8(sZ + rowA * 136 + ks * 32 + g * 8);
        int kb = ks * 4 + g;
        short8 B0 = ld8(sW + kb * 512 + col0 * 8);
        short8 B1 = ld8(sW + kb * 512 + col1 * 8);
        aq0 = MFMA(A, B0, aq0);
        aq1 = MFMA(A, B1, aq1);
    }
    float qv[2][4], qg[2][4], qb[2][4];
    {
        float zr_[4], zrm_[4];
        #pragma unroll
        for (int r = 0; r < 4; ++r) { zr_[r] = sZr[rowC[r]]; zrm_[r] = sZrm[rowC[r]]; }
        float GQ0 = sAux[col0], BQ0 = sAux[64 + col0];
        float GQ1 = sAux[col1], BQ1 = sAux[64 + col1];
        #pragma unroll
        for (int r = 0; r < 4; ++r) {
            qv[0][r] = fmaf(zr_[r], aq0[r], fmaf(-zrm_[r], GQ0, BQ0));
            qv[1][r] = fmaf(zr_[r], aq1[r], fmaf(-zrm_[r], GQ1, BQ1));
        }
        float GK0 = sAux[128 + col0], BK0 = sAux[192 + col0];
        float GK1 = sAux[128 + col1], BK1 = sAux[192 + col1];
        #pragma unroll
        for (int r = 0; r < 4; ++r) {
            qg[0][r] = red16(qv[0][r] * GK0);
            qb[0][r] = red16(qv[0][r] * BK0);
            qg[1][r] = red16(qv[1][r] * GK1);
            qb[1][r] = red16(qv[1][r] * BK1);
        }
    }
    __syncthreads();
    {   // restage weights: Wk -> sW[0,4096), Wv -> sW[4096,8192)
        const uint4* src = (const uint4*)wsu;
        uint4* dst = (uint4*)sW;
        dst[tid]       = src[1024 + tid];
        dst[256 + tid] = src[1280 + tid];
        dst[512 + tid] = src[1536 + tid];
        dst[768 + tid] = src[1792 + tid];
    }
    __syncthreads();

    // ================= phase 2: k GEMMs + logits =================
    float lg[4][2][4], pmr[4][4];
    #pragma unroll
    for (int tt = 0; tt < 4; ++tt) {
        f4 k0 = {0.f,0.f,0.f,0.f}, k1 = {0.f,0.f,0.f,0.f};
        const u16* At = sT + tt * 2304;
        #pragma unroll
        for (int ks = 0; ks < 2; ++ks) {
            short8 A = ld8(At + rowA * 72 + ks * 32 + g * 8);
            int kb = ks * 4 + g;
            short8 B0 = ld8(sW + kb * 512 + col0 * 8);
            short8 B1 = ld8(sW + kb * 512 + col1 * 8);
            k0 = MFMA(A, B0, k0);
            k1 = MFMA(A, B1, k1);
        }
        float tr_[4], trm_[4];
        #pragma unroll
        for (int r = 0; r < 4; ++r) {
            tr_[r] = sTr[tt * 32 + rowC[r]];
            trm_[r] = sTrm[tt * 32 + rowC[r]];
            pmr[tt][r] = sPm[tt * 32 + rowC[r]];
        }
        #pragma unroll
        for (int r = 0; r < 4; ++r) {
            float raw0 = red16(qv[0][r] * k0[r]);
            float raw1 = red16(qv[1][r] * k1[r]);
            float l0 = 0.25f * fmaf(tr_[r], raw0, fmaf(-trm_[r], qg[0][r], qb[0][r]));
            float l1 = 0.25f * fmaf(tr_[r], raw1, fmaf(-trm_[r], qg[1][r], qb[1][r]));
            lg[tt][0][r] = (pmr[tt][r] == 0.f) ? -1e9f : l0;
            lg[tt][1][r] = (pmr[tt][r] == 0.f) ? -1e9f : l1;
        }
    }

    // ================= phase 3: softmax over T (in-lane) =================
    float ap[4][2][4], cb[2][4], cg[2][4];
    #pragma unroll
    for (int r = 0; r < 4; ++r) {
        float trA[4], trmA[4];
        #pragma unroll
        for (int tt = 0; tt < 4; ++tt) {
            trA[tt] = sTr[tt * 32 + rowC[r]];
            trmA[tt] = sTrm[tt * 32 + rowC[r]];
        }
        #pragma unroll
        for (int nn = 0; nn < 2; ++nn) {
            float l0 = lg[0][nn][r], l1 = lg[1][nn][r], l2 = lg[2][nn][r], l3 = lg[3][nn][r];
            float mx = fmaxf(fmaxf(l0, l1), fmaxf(l2, l3));
            float e0 = __expf(l0 - mx), e1 = __expf(l1 - mx), e2 = __expf(l2 - mx), e3 = __expf(l3 - mx);
            float inv = 1.f / (e0 + e1 + e2 + e3);
            float a0 = e0 * inv * pmr[0][r], a1 = e1 * inv * pmr[1][r];
            float a2 = e2 * inv * pmr[2][r], a3 = e3 * inv * pmr[3][r];
            float ssum = a0 + a1 + a2 + a3;
            float rr = 1.f / fmaxf(ssum, 1e-8f);
            a0 *= rr; a1 *= rr; a2 *= rr; a3 *= rr;
            cb[nn][r] = a0 + a1 + a2 + a3;
            cg[nn][r] = a0 * trmA[0] + a1 * trmA[1] + a2 * trmA[2] + a3 * trmA[3];
            ap[0][nn][r] = a0 * trA[0]; ap[1][nn][r] = a1 * trA[1];
            ap[2][nn][r] = a2 * trA[2]; ap[3][nn][r] = a3 * trA[3];
        }
    }

    // ================= phase 4: v GEMMs + weighted accumulate =================
    float o_[2][4] = {{0.f,0.f,0.f,0.f},{0.f,0.f,0.f,0.f}};
    const u16* sWv = sW + 4096;
    #pragma unroll
    for (int tt = 0; tt < 4; ++tt) {
        f4 v0 = {0.f,0.f,0.f,0.f}, v1 = {0.f,0.f,0.f,0.f};
        const u16* At = sT + tt * 2304;
        #pragma unroll
        for (int ks = 0; ks < 2; ++ks) {
            short8 A = ld8(At + rowA * 72 + ks * 32 + g * 8);
            int kb = ks * 4 + g;
            short8 B0 = ld8(sWv + kb * 512 + col0 * 8);
            short8 B1 = ld8(sWv + kb * 512 + col1 * 8);
            v0 = MFMA(A, B0, v0);
            v1 = MFMA(A, B1, v1);
        }
        #pragma unroll
        for (int r = 0; r < 4; ++r) {
            o_[0][r] = fmaf(ap[tt][0][r], v0[r], o_[0][r]);
            o_[1][r] = fmaf(ap[tt][1][r], v1[r], o_[1][r]);
        }
    }
    {   // LN affine correction for v
        float GV0 = sAux[256 + col0], BV0 = sAux[320 + col0];
        float GV1 = sAux[256 + col1], BV1 = sAux[320 + col1];
        #pragma unroll
        for (int r = 0; r < 4; ++r) {
            o_[0][r] = fmaf(cb[0][r], BV0, fmaf(-cg[0][r], GV0, o_[0][r]));
            o_[1][r] = fmaf(cb[1][r], BV1, fmaf(-cg[1][r], GV1, o_[1][r]));
        }
    }
    __syncthreads();   // everyone done with sW (Wv) and sZ (z)
    {   // write o (bf16, stride 72) into sZ region; restage Wo -> sW
        #pragma unroll
        for (int r = 0; r < 4; ++r) {
            sZ[rowC[r] * 72 + col0] = f2bf(o_[0][r]);
            sZ[rowC[r] * 72 + col1] = f2bf(o_[1][r]);
        }
        const uint4* src = (const uint4*)wsu;
        uint4* dst = (uint4*)sW;
        #pragma unroll
        for (int r = 0; r < 4; ++r) dst[tid + 256 * r] = src[2048 + tid + 256 * r];
    }
    __syncthreads();

    // ================= phase 5: out GEMM [32x64]@[64x128] =================
    {
        const int rt2 = wave & 1;
        const int nb = (wave >> 1) * 4;      // 4 n-tiles per wave
        f4 c0 = {0.f,0.f,0.f,0.f}, c1 = {0.f,0.f,0.f,0.f};
        f4 c2 = {0.f,0.f,0.f,0.f}, c3 = {0.f,0.f,0.f,0.f};
        #pragma unroll
        for (int ks = 0; ks < 2; ++ks) {
            short8 A = ld8(sZ + (rt2 * 16 + l15) * 72 + ks * 32 + g * 8);
            int kb = ks * 4 + g;
            short8 B0 = ld8(sW + kb * 1024 + ((nb + 0) * 16 + l15) * 8);
            short8 B1 = ld8(sW + kb * 1024 + ((nb + 1) * 16 + l15) * 8);
            short8 B2 = ld8(sW + kb * 1024 + ((nb + 2) * 16 + l15) * 8);
            short8 B3 = ld8(sW + kb * 1024 + ((nb + 3) * 16 + l15) * 8);
            c0 = MFMA(A, B0, c0); c1 = MFMA(A, B1, c1);
            c2 = MFMA(A, B2, c2); c3 = MFMA(A, B3, c3);
        }
        #pragma unroll
        for (int r = 0; r < 4; ++r) {
            int row = p0 + rt2 * 16 + g * 4 + r;
            float* op = out + (size_t)row * 128;
            op[(nb + 0) * 16 + l15] = c0[r] + sBo[(nb + 0) * 16 + l15];
            op[(nb + 1) * 16 + l15] = c1[r] + sBo[(nb + 1) * 16 + l15];
            op[(nb + 2) * 16 + l15] = c2[r] + sBo[(nb + 2) * 16 + l15];
            op[(nb + 3) * 16 + l15] = c3[r] + sBo[(nb + 3) * 16 + l15];
        }
    }
}

extern "C" void kernel_launch(void* const* d_in, const int* in_sizes, int n_in,
                              void* d_out, int out_size, void* d_ws, size_t ws_size,
                              hipStream_t stream) {
    const float* t   = (const float*)d_in[0];
    const float* z   = (const float*)d_in[1];
    const float* msk = (const float*)d_in[2];
    const float* zg  = (const float*)d_in[3];
    const float* zb  = (const float*)d_in[4];
    const float* tg  = (const float*)d_in[5];
    const float* tb  = (const float*)d_in[6];
    const float* Wq  = (const float*)d_in[7];
    const float* Wk  = (const float*)d_in[8];
    const float* Wv  = (const float*)d_in[9];
    const float* Wo  = (const float*)d_in[10];
    const float* bo  = (const float*)d_in[11];
    float* ws = (float*)d_ws;

    prep_w<<<96, 256, 0, stream>>>(Wq, Wk, Wv, Wo, zg, tg, ws);
    prep_aux<<<2, 256, 0, stream>>>(Wq, Wk, Wv, zg, zb, tg, tb, bo, ws);
    tpa_main<<<4608, 256, 0, stream>>>(t, z, msk, ws, (float*)d_out);
}